// Round 4
// baseline (1824.727 us; speedup 1.0000x reference)
//
#include <hip/hip_runtime.h>

#define HID 128
#define OUTD 64
#define N_SOTU 500000
#define N_TAXON 200000
#define E_TT 200000
#define E_TS 1000000
#define E_LBL 500000
#define SCAN_TILE 2048   // elements per scan block (256 thr x 8)

typedef short s16x8 __attribute__((ext_vector_type(8)));   // 8 bf16 (4 VGPRs) MFMA frag
typedef float f32x4 __attribute__((ext_vector_type(4)));

__device__ __forceinline__ unsigned short f2bf(float f) {  // f32 -> bf16 bits, RNE
    unsigned u = __builtin_bit_cast(unsigned, f);
    u += 0x7FFFu + ((u >> 16) & 1u);
    return (unsigned short)(u >> 16);
}
__device__ __forceinline__ float bf2f(unsigned short h) {
    unsigned u = ((unsigned)h) << 16;
    return __builtin_bit_cast(float, u);
}

// =================== embedding f32 -> bf16 (with id gather) ===================
// one thread per 8 features
__global__ __launch_bounds__(256) void conv_kernel(const float* __restrict__ emb,
                                                   const int* __restrict__ ids, int n_rows,
                                                   unsigned short* __restrict__ outb) {
    int t = blockIdx.x * 256 + threadIdx.x;
    int row = t >> 4;
    if (row >= n_rows) return;
    int part = t & 15;
    const float* p = emb + (size_t)ids[row] * HID + part * 8;
    float4 v0 = *(const float4*)p;
    float4 v1 = *(const float4*)(p + 4);
    s16x8 o;
    o[0] = (short)f2bf(v0.x); o[1] = (short)f2bf(v0.y); o[2] = (short)f2bf(v0.z); o[3] = (short)f2bf(v0.w);
    o[4] = (short)f2bf(v1.x); o[5] = (short)f2bf(v1.y); o[6] = (short)f2bf(v1.z); o[7] = (short)f2bf(v1.w);
    *(s16x8*)(outb + (size_t)row * HID + part * 8) = o;
}

// =================== CSR build: hist -> scan (3 kernels) -> fill ===================
__global__ void hist_kernel(const int* __restrict__ dst, int n, int* __restrict__ rp) {
    int e = blockIdx.x * 256 + threadIdx.x;
    if (e < n) atomicAdd(&rp[dst[e]], 1);
}

__global__ __launch_bounds__(256) void scan1_kernel(int* __restrict__ a, int n, int* __restrict__ bsums) {
    __shared__ int tsum[256];
    const int t = threadIdx.x;
    const int base = blockIdx.x * SCAN_TILE + t * 8;
    int v[8]; int s = 0;
#pragma unroll
    for (int i = 0; i < 8; i++) {
        int x = (base + i < n) ? a[base + i] : 0;
        s += x; v[i] = s;
    }
    tsum[t] = s;
    __syncthreads();
    for (int off = 1; off < 256; off <<= 1) {
        int x = (t >= off) ? tsum[t - off] : 0;
        __syncthreads();
        tsum[t] += x;
        __syncthreads();
    }
    const int prev = (t > 0) ? tsum[t - 1] : 0;
#pragma unroll
    for (int i = 0; i < 8; i++)
        if (base + i < n) a[base + i] = v[i] + prev;
    if (t == 255) bsums[blockIdx.x] = tsum[255];
}

__global__ __launch_bounds__(256) void scan2_kernel(int* __restrict__ bsums, int nb) {
    __shared__ int tsum[256];
    const int t = threadIdx.x;
    tsum[t] = (t < nb) ? bsums[t] : 0;
    __syncthreads();
    for (int off = 1; off < 256; off <<= 1) {
        int x = (t >= off) ? tsum[t - off] : 0;
        __syncthreads();
        tsum[t] += x;
        __syncthreads();
    }
    if (t < nb) bsums[t] = tsum[t];
}

__global__ __launch_bounds__(256) void scan3_kernel(int* __restrict__ a, int n, const int* __restrict__ bsums) {
    const int b = blockIdx.x;
    if (b == 0) return;
    const int add = bsums[b - 1];
    const int base = b * SCAN_TILE + threadIdx.x * 8;
#pragma unroll
    for (int i = 0; i < 8; i++)
        if (base + i < n) a[base + i] += add;
}

// fill buckets back-to-front; afterwards rp[d] = bucket start
__global__ void fill_kernel(const int* __restrict__ src, const int* __restrict__ dst, int n,
                            int* __restrict__ rp, int* __restrict__ sl) {
    int e = blockIdx.x * 256 + threadIdx.x;
    if (e < n) {
        int pos = atomicSub(&rp[dst[e]], 1) - 1;
        sl[pos] = src[e];
    }
}

// =================== fused gather + SAGE: out = relu( mean_nbr(xa) @ wl + xd @ wr + bl ) ========
// MFMA 16x16x32 bf16, K=256 (concat [mean | x_dst]), N=128. Weights bf16 in LDS, transposed +
// XOR-granule-swizzled. Each wave owns 16 dst rows: walks their CSR buckets, accumulating the
// mean directly into its A-fragment registers (no agg buffer). xa must NOT alias out.
__device__ __forceinline__ int wt_idx(int n, int k) {
    return n * 256 + ((((k >> 3) ^ n) & 31) << 3) + (k & 7);
}

__global__ __launch_bounds__(256) void fsage_kernel(
    int n_rows,
    const int* __restrict__ rp, const int* __restrict__ sl, int n_edges,
    const unsigned short* __restrict__ xa,   // gather source rows (bf16)
    const unsigned short* __restrict__ xd,   // dst-side x rows (bf16)
    const float* __restrict__ wl, const float* __restrict__ wr,
    const float* __restrict__ bl,
    unsigned short* __restrict__ out)
{
    __shared__ __align__(16) unsigned short WT[128 * 256];  // 64 KB: WT[n][k], k<128 wl, k>=128 wr
    for (int idx = threadIdx.x; idx < 128 * 128; idx += 256) {
        int n = idx & 127, k = idx >> 7;
        WT[wt_idx(n, k)]       = f2bf(wl[idx]);   // wl[k][n]
        WT[wt_idx(n, k + 128)] = f2bf(wr[idx]);   // wr[k][n]
    }
    __syncthreads();
    const int lane = threadIdx.x & 63, wid = threadIdx.x >> 6;
    const int l16 = lane & 15, q = lane >> 4;
    const int n_tiles = n_rows >> 4;
    const int stride = gridDim.x * 4;
    for (int tile = blockIdx.x * 4 + wid; tile < n_tiles; tile += stride) {
        const int base = tile << 4;
        const int row = base + l16;          // this lane's dst row (A-operand m index)
        const int start = rp[row];
        const int end = (row + 1 < n_rows) ? rp[row + 1] : n_edges;
        // gather-mean into registers: lane accumulates feats {ks*32 + q*8 + i}
        float ga[32];
#pragma unroll
        for (int i = 0; i < 32; i++) ga[i] = 0.0f;
        for (int j = start; j < end; ++j) {
            const size_t s = (size_t)sl[j];
#pragma unroll
            for (int ks = 0; ks < 4; ks++) {
                s16x8 v = *(const s16x8*)(xa + s * HID + ks * 32 + q * 8);
#pragma unroll
                for (int i = 0; i < 8; i++) ga[ks * 8 + i] += bf2f((unsigned short)v[i]);
            }
        }
        const float inv = (end > start) ? 1.0f / (float)(end - start) : 0.0f;
        f32x4 acc[8] = {};
        // K = 0..127 : mean aggregation from registers
#pragma unroll
        for (int ks = 0; ks < 4; ks++) {
            s16x8 a;
#pragma unroll
            for (int i = 0; i < 8; i++) a[i] = (short)f2bf(ga[ks * 8 + i] * inv);
            const int kb = ks * 32 + q * 8;
#pragma unroll
            for (int nt = 0; nt < 8; nt++) {
                s16x8 b = *(const s16x8*)&WT[wt_idx(nt * 16 + l16, kb)];
                acc[nt] = __builtin_amdgcn_mfma_f32_16x16x32_bf16(a, b, acc[nt], 0, 0, 0);
            }
        }
        // K = 128..255 : x_dst
#pragma unroll
        for (int ks = 0; ks < 4; ks++) {
            s16x8 a = *(const s16x8*)(xd + (size_t)row * HID + ks * 32 + q * 8);
            const int kb = 128 + ks * 32 + q * 8;
#pragma unroll
            for (int nt = 0; nt < 8; nt++) {
                s16x8 b = *(const s16x8*)&WT[wt_idx(nt * 16 + l16, kb)];
                acc[nt] = __builtin_amdgcn_mfma_f32_16x16x32_bf16(a, b, acc[nt], 0, 0, 0);
            }
        }
        // epilogue. D layout (m89-verified): col = lane&15, row = (lane>>4)*4 + i
#pragma unroll
        for (int nt = 0; nt < 8; nt++) {
            const int n = nt * 16 + l16;
            const float bv = bl[n];
#pragma unroll
            for (int i = 0; i < 4; i++) {
                float v = acc[nt][i] + bv;
                out[(size_t)(base + q * 4 + i) * HID + n] = f2bf(fmaxf(v, 0.0f));
            }
        }
    }
}

// =================== linear head: z = x @ w + b  ([N,128]@[128,64]) ===================
__global__ __launch_bounds__(256) void proj_kernel(
    int n_nodes, const unsigned short* __restrict__ x,
    const float* __restrict__ w, const float* __restrict__ bias, unsigned short* __restrict__ z)
{
    const int lane = threadIdx.x & 63, wid = threadIdx.x >> 6;
    const int l16 = lane & 15, q = lane >> 4;
    s16x8 bfr[4][4];
#pragma unroll
    for (int ks = 0; ks < 4; ks++)
#pragma unroll
        for (int nt = 0; nt < 4; nt++)
#pragma unroll
            for (int i = 0; i < 8; i++)
                bfr[ks][nt][i] = (short)f2bf(w[(ks * 32 + q * 8 + i) * OUTD + nt * 16 + l16]);
    const int n_tiles = n_nodes >> 4;
    const int stride = gridDim.x * 4;
    for (int tile = blockIdx.x * 4 + wid; tile < n_tiles; tile += stride) {
        const int base = tile << 4;
        const size_t mrow = (size_t)(base + l16);
        f32x4 acc[4] = {};
#pragma unroll
        for (int ks = 0; ks < 4; ks++) {
            s16x8 a = *(const s16x8*)(x + mrow * HID + ks * 32 + q * 8);
#pragma unroll
            for (int nt = 0; nt < 4; nt++)
                acc[nt] = __builtin_amdgcn_mfma_f32_16x16x32_bf16(a, bfr[ks][nt], acc[nt], 0, 0, 0);
        }
#pragma unroll
        for (int nt = 0; nt < 4; nt++) {
            const int n = nt * 16 + l16;
            const float bv = bias[n];
#pragma unroll
            for (int i = 0; i < 4; i++)
                z[(size_t)(base + q * 4 + i) * OUTD + n] = f2bf(acc[nt][i] + bv);
        }
    }
}

// =================== edge decoder ===================
__global__ __launch_bounds__(256) void dec_kernel(
    const int* __restrict__ erow, const int* __restrict__ ecol,
    const unsigned short* __restrict__ zs, const unsigned short* __restrict__ zt,
    const float* __restrict__ w1, const float* __restrict__ b1,
    const float* __restrict__ w2, const float* __restrict__ b2,
    float* __restrict__ out)
{
    const int lane = threadIdx.x & 63, wid = threadIdx.x >> 6;
    const int l16 = lane & 15, q = lane >> 4;
    s16x8 bfr[4][4];  // d1_w [128][64] as B-fragments
#pragma unroll
    for (int ks = 0; ks < 4; ks++)
#pragma unroll
        for (int nt = 0; nt < 4; nt++)
#pragma unroll
            for (int i = 0; i < 8; i++)
                bfr[ks][nt][i] = (short)f2bf(w1[(ks * 32 + q * 8 + i) * OUTD + nt * 16 + l16]);
    float b1v[4], w2v[4];
#pragma unroll
    for (int nt = 0; nt < 4; nt++) {
        b1v[nt] = b1[nt * 16 + l16];
        w2v[nt] = w2[nt * 16 + l16];
    }
    const float b2v = b2[0];
    const int n_tiles = E_LBL >> 4;
    for (int tile = blockIdx.x * 4 + wid; tile < n_tiles; tile += gridDim.x * 4) {
        const int em = tile * 16 + l16;
        const size_t r = (size_t)erow[em], c = (size_t)ecol[em];
        f32x4 acc[4] = {};
        s16x8 a0 = *(const s16x8*)(zs + r * OUTD + q * 8);
        s16x8 a1 = *(const s16x8*)(zs + r * OUTD + 32 + q * 8);
        s16x8 a2 = *(const s16x8*)(zt + c * OUTD + q * 8);
        s16x8 a3 = *(const s16x8*)(zt + c * OUTD + 32 + q * 8);
#pragma unroll
        for (int nt = 0; nt < 4; nt++) {
            acc[nt] = __builtin_amdgcn_mfma_f32_16x16x32_bf16(a0, bfr[0][nt], acc[nt], 0, 0, 0);
            acc[nt] = __builtin_amdgcn_mfma_f32_16x16x32_bf16(a1, bfr[1][nt], acc[nt], 0, 0, 0);
            acc[nt] = __builtin_amdgcn_mfma_f32_16x16x32_bf16(a2, bfr[2][nt], acc[nt], 0, 0, 0);
            acc[nt] = __builtin_amdgcn_mfma_f32_16x16x32_bf16(a3, bfr[3][nt], acc[nt], 0, 0, 0);
        }
        float s[4] = {0.0f, 0.0f, 0.0f, 0.0f};
#pragma unroll
        for (int nt = 0; nt < 4; nt++)
#pragma unroll
            for (int i = 0; i < 4; i++)
                s[i] += fmaxf(acc[nt][i] + b1v[nt], 0.0f) * w2v[nt];
#pragma unroll
        for (int off = 8; off >= 1; off >>= 1)
#pragma unroll
            for (int i = 0; i < 4; i++)
                s[i] += __shfl_down(s[i], off, 16);
        if (l16 == 0) {
#pragma unroll
            for (int i = 0; i < 4; i++)
                out[tile * 16 + q * 4 + i] = s[i] + b2v;
        }
    }
}

// =================== host side ===================
static void build_csr(const int* src, const int* dst, int n_edges, int n_dst,
                      int* rp, int* sl, int* bsums, hipStream_t stream) {
    hipMemsetAsync(rp, 0, (size_t)n_dst * 4, stream);
    hist_kernel<<<(n_edges + 255) / 256, 256, 0, stream>>>(dst, n_edges, rp);
    const int nb = (n_dst + SCAN_TILE - 1) / SCAN_TILE;   // <= 245, fits scan2's 256
    scan1_kernel<<<nb, 256, 0, stream>>>(rp, n_dst, bsums);
    scan2_kernel<<<1, 256, 0, stream>>>(bsums, nb);
    scan3_kernel<<<nb, 256, 0, stream>>>(rp, n_dst, bsums);
    fill_kernel<<<(n_edges + 255) / 256, 256, 0, stream>>>(src, dst, n_edges, rp, sl);
}

extern "C" void kernel_launch(void* const* d_in, const int* in_sizes, int n_in,
                              void* d_out, int out_size, void* d_ws, size_t ws_size,
                              hipStream_t stream) {
    (void)in_sizes; (void)n_in; (void)out_size; (void)ws_size;
    const int* sotu_ids  = (const int*)d_in[0];
    const int* taxon_ids = (const int*)d_in[1];
    const int* ett_src   = (const int*)d_in[2];
    const int* ett_dst   = (const int*)d_in[3];
    const int* ets_src   = (const int*)d_in[4];
    const int* ets_dst   = (const int*)d_in[5];
    const int* elbl_row  = (const int*)d_in[6];
    const int* elbl_col  = (const int*)d_in[7];
    const float* sotu_emb  = (const float*)d_in[8];
    const float* taxon_emb = (const float*)d_in[9];
    const float* s1_wl = (const float*)d_in[10]; const float* s1_bl = (const float*)d_in[11]; const float* s1_wr = (const float*)d_in[12];
    const float* s2_wl = (const float*)d_in[13]; const float* s2_bl = (const float*)d_in[14]; const float* s2_wr = (const float*)d_in[15];
    const float* s3_wl = (const float*)d_in[16]; const float* s3_bl = (const float*)d_in[17]; const float* s3_wr = (const float*)d_in[18];
    const float* sl_w  = (const float*)d_in[19]; const float* sl_b  = (const float*)d_in[20];
    const float* t1_wl = (const float*)d_in[21]; const float* t1_bl = (const float*)d_in[22]; const float* t1_wr = (const float*)d_in[23];
    const float* t2_wl = (const float*)d_in[24]; const float* t2_bl = (const float*)d_in[25]; const float* t2_wr = (const float*)d_in[26];
    const float* tl_w  = (const float*)d_in[27]; const float* tl_b  = (const float*)d_in[28];
    const float* d1_w  = (const float*)d_in[29]; const float* d1_b  = (const float*)d_in[30];
    const float* d2_w  = (const float*)d_in[31]; const float* d2_b  = (const float*)d_in[32];
    float* out = (float*)d_out;

    // workspace (~690 MB of the 1.024 GB pool; observed via the harness's 1.024e9 B poison fill)
    char* ws = (char*)d_ws;
    size_t off = 0;
    auto alloc = [&](size_t bytes) { void* p = ws + off; off = (off + bytes + 255) & ~(size_t)255; return p; };
    unsigned short* xb_taxon = (unsigned short*)alloc((size_t)N_TAXON * HID * 2);  // 51.2 MB
    unsigned short* xb_sotu  = (unsigned short*)alloc((size_t)N_SOTU * HID * 2);   // 128 MB
    unsigned short* taxon_x  = (unsigned short*)alloc((size_t)N_TAXON * HID * 2);  // 51.2 MB
    unsigned short* tx1      = (unsigned short*)alloc((size_t)N_TAXON * HID * 2);  // 51.2 MB
    unsigned short* tx2      = (unsigned short*)alloc((size_t)N_TAXON * HID * 2);  // 51.2 MB
    unsigned short* sotu_x   = (unsigned short*)alloc((size_t)N_SOTU * HID * 2);   // 128 MB
    unsigned short* sotu_x2  = (unsigned short*)alloc((size_t)N_SOTU * HID * 2);   // 128 MB
    unsigned short* z_taxon  = (unsigned short*)alloc((size_t)N_TAXON * OUTD * 2); // 25.6 MB
    unsigned short* z_sotu   = (unsigned short*)alloc((size_t)N_SOTU * OUTD * 2);  // 64 MB
    int* rp_ts = (int*)alloc((size_t)N_SOTU * 4);    // 2 MB
    int* sl_ts = (int*)alloc((size_t)E_TS * 4);      // 4 MB
    int* rp_tt = (int*)alloc((size_t)N_TAXON * 4);   // 0.8 MB
    int* sl_tt = (int*)alloc((size_t)E_TT * 4);      // 0.8 MB
    int* bsums = (int*)alloc(256 * 4);

    // one-time bf16 conversion (+ id gather) of the embedding tables
    conv_kernel<<<(N_TAXON * 16 + 255) / 256, 256, 0, stream>>>(taxon_emb, taxon_ids, N_TAXON, xb_taxon);
    conv_kernel<<<(N_SOTU * 16 + 255) / 256, 256, 0, stream>>>(sotu_emb, sotu_ids, N_SOTU, xb_sotu);

    // CSR builds (tt used by s1/t1/t2; ts by s2/s3)
    build_csr(ett_src, ett_dst, E_TT, N_TAXON, rp_tt, sl_tt, bsums, stream);
    build_csr(ets_src, ets_dst, E_TS, N_SOTU, rp_ts, sl_ts, bsums, stream);

    // s1 / t1 : mean_{ett} xb_taxon (gathered per-wave), x = xb_taxon
    fsage_kernel<<<512, 256, 0, stream>>>(N_TAXON, rp_tt, sl_tt, E_TT, xb_taxon, xb_taxon,
                                          s1_wl, s1_wr, s1_bl, taxon_x);
    fsage_kernel<<<512, 256, 0, stream>>>(N_TAXON, rp_tt, sl_tt, E_TT, xb_taxon, xb_taxon,
                                          t1_wl, t1_wr, t1_bl, tx1);
    // t2 : mean_{ett} tx1, x = tx1 -> tx2 (must not write in place: gather reads other rows)
    fsage_kernel<<<512, 256, 0, stream>>>(N_TAXON, rp_tt, sl_tt, E_TT, tx1, tx1,
                                          t2_wl, t2_wr, t2_bl, tx2);
    proj_kernel<<<1024, 256, 0, stream>>>(N_TAXON, tx2, tl_w, tl_b, z_taxon);

    // s2 : mean_{ets} xb_taxon -> sotu, x = xb_sotu
    fsage_kernel<<<512, 256, 0, stream>>>(N_SOTU, rp_ts, sl_ts, E_TS, xb_taxon, xb_sotu,
                                          s2_wl, s2_wr, s2_bl, sotu_x);
    // s3 : mean_{ets} taxon_x -> sotu, x = sotu_x -> sotu_x2
    fsage_kernel<<<512, 256, 0, stream>>>(N_SOTU, rp_ts, sl_ts, E_TS, taxon_x, sotu_x,
                                          s3_wl, s3_wr, s3_bl, sotu_x2);
    proj_kernel<<<1024, 256, 0, stream>>>(N_SOTU, sotu_x2, sl_w, sl_b, z_sotu);

    // edge decoder
    dec_kernel<<<1024, 256, 0, stream>>>(elbl_row, elbl_col, z_sotu, z_taxon,
                                         d1_w, d1_b, d2_w, d2_b, out);
}